// Round 2
// baseline (13133.311 us; speedup 1.0000x reference)
//
#include <hip/hip_runtime.h>
#include <hip/hip_bf16.h>

#define BB    512
#define TTT   336
#define EE    256
#define LHH   512
#define NHH   8
#define DHH   32
#define PSS   48
#define STARTT 336
#define INP1  325   // 5 + 64 + 256
#define NCOV  5

typedef __hip_bfloat16 bf16;

__device__ __forceinline__ float sigf(float x) { return 1.f / (1.f + __expf(-x)); }
__device__ __forceinline__ float bf2lo(unsigned u) { return __uint_as_float(u << 16); }
__device__ __forceinline__ float bf2hi(unsigned u) { return __uint_as_float(u & 0xffff0000u); }

// ---------------- init kernels ----------------
__global__ void k_zero(float* __restrict__ p, int n) {
    for (int i = blockIdx.x * blockDim.x + threadIdx.x; i < n; i += gridDim.x * blockDim.x)
        p[i] = 0.f;
}

// inp layout per row b (325 cols): [0..4]=x_t, [5..68]=idx_embed, [69..324]=ctx
__global__ void k_init_inp(float* __restrict__ inp, const float* __restrict__ idx_embed,
                           const float* __restrict__ zxs) {
    int i = blockIdx.x * blockDim.x + threadIdx.x;
    if (i >= BB * INP1) return;
    int b = i / INP1, k = i % INP1;
    float v;
    if (k < NCOV)      v = zxs[b * ((STARTT + PSS) * NCOV) + STARTT * NCOV + k];  // x_0
    else if (k < 69)   v = idx_embed[b * 64 + (k - 5)];
    else               v = 0.f;                                                   // ctx_0 = 0
    inp[i] = v;
}

__global__ void k_bsum(const float* __restrict__ a, const float* __restrict__ b,
                       float* __restrict__ o, int n) {
    int i = blockIdx.x * blockDim.x + threadIdx.x;
    if (i < n) o[i] = a[i] + b[i];
}

// ---------------- generic tiled GEMM: C = A1@W1.T [+ A2@W2.T] + bias ----------------
// A (M x K) row-major with leading dim lda; W (N x K) row-major; C (M x N) ldc.
// 64x64 tile, 256 threads, 4x4 microtile. M,N multiples of 64; K arbitrary (guarded).
template<bool TWO, bool OBF16>
__global__ __launch_bounds__(256)
void k_gemm(const float* __restrict__ A1, int lda1, const float* __restrict__ W1, int K1,
            const float* __restrict__ A2, int lda2, const float* __restrict__ W2, int K2,
            const float* __restrict__ bias, void* __restrict__ Cv, int ldc) {
    __shared__ float As[16][68];
    __shared__ float Ws[16][68];
    const int tid = threadIdx.x;
    const int row0 = blockIdx.x * 64;
    const int col0 = blockIdx.y * 64;
    const int lr = tid >> 2;          // 0..63: tile row (A) / tile col (W)
    const int lk = (tid & 3) << 2;    // 0,4,8,12
    const int tx = tid & 15, ty = tid >> 4;
    float acc[4][4] = {};

    const int nph = TWO ? 2 : 1;
    for (int ph = 0; ph < nph; ++ph) {
        const float* A = ph ? A2 : A1;
        const float* W = ph ? W2 : W1;
        const int K   = ph ? K2 : K1;
        const int lda = ph ? lda2 : lda1;
        const int nk = (K + 15) >> 4;
        for (int kt = 0; kt < nk; ++kt) {
            const int k0 = kt << 4;
            const float* ar = A + (size_t)(row0 + lr) * lda + k0 + lk;
            const float* wr = W + (size_t)(col0 + lr) * K + k0 + lk;
            #pragma unroll
            for (int j = 0; j < 4; ++j) {
                const int kk = k0 + lk + j;
                As[lk + j][lr] = (kk < K) ? ar[j] : 0.f;
                Ws[lk + j][lr] = (kk < K) ? wr[j] : 0.f;
            }
            __syncthreads();
            #pragma unroll
            for (int kk = 0; kk < 16; ++kk) {
                float a[4], w[4];
                #pragma unroll
                for (int i = 0; i < 4; ++i) a[i] = As[kk][ty * 4 + i];
                #pragma unroll
                for (int j = 0; j < 4; ++j) w[j] = Ws[kk][tx * 4 + j];
                #pragma unroll
                for (int i = 0; i < 4; ++i)
                    #pragma unroll
                    for (int j = 0; j < 4; ++j)
                        acc[i][j] += a[i] * w[j];
            }
            __syncthreads();
        }
    }
    if (OBF16) {
        bf16* C = (bf16*)Cv;
        #pragma unroll
        for (int i = 0; i < 4; ++i)
            #pragma unroll
            for (int j = 0; j < 4; ++j) {
                const int r = row0 + ty * 4 + i, c = col0 + tx * 4 + j;
                C[(size_t)r * ldc + c] = __float2bfloat16(acc[i][j] + bias[c]);
            }
    } else {
        float* C = (float*)Cv;
        #pragma unroll
        for (int i = 0; i < 4; ++i)
            #pragma unroll
            for (int j = 0; j < 4; ++j) {
                const int r = row0 + ty * 4 + i, c = col0 + tx * 4 + j;
                C[(size_t)r * ldc + c] = acc[i][j] + bias[c];
            }
    }
}

// ---------------- LSTM pointwise: h,c update from gates (B x 4H) ----------------
__global__ void k_lstm_pw(const float* __restrict__ gates, float* __restrict__ h,
                          float* __restrict__ c, int H) {
    int i = blockIdx.x * blockDim.x + threadIdx.x;
    if (i >= BB * H) return;
    int b = i / H, j = i % H;
    const float* g = gates + (size_t)b * 4 * H;
    float ig = sigf(g[j]);
    float fg = sigf(g[H + j]);
    float gg = tanhf(g[2 * H + j]);
    float og = sigf(g[3 * H + j]);
    float cn = fg * c[i] + ig * gg;
    c[i] = cn;
    h[i] = og * tanhf(cn);
}

// ---------------- attention: q-proj + scores + softmax + PV, one block per batch row ----------------
__global__ __launch_bounds__(256)
void k_attn(const float* __restrict__ h2, const float* __restrict__ wq, const float* __restrict__ bq,
            const bf16* __restrict__ kp, const bf16* __restrict__ vp,
            float* __restrict__ actx, float* __restrict__ attn_out, int step) {
    const int b = blockIdx.x;
    const int tid = threadIdx.x;
    __shared__ float h2s[EE];
    __shared__ float qs[EE];
    __shared__ float s[NHH][TTT];

    h2s[tid] = h2[(size_t)b * EE + tid];
    __syncthreads();

    // q projection (scale 1/sqrt(DH) folded into q)
    {
        const float* wr = wq + (size_t)tid * EE;
        float acc = bq[tid];
        #pragma unroll 8
        for (int i = 0; i < EE; ++i) acc += h2s[i] * wr[i];
        qs[tid] = acc * 0.17677669529663689f;
    }
    __syncthreads();

    // scores: 8 heads x 336 keys
    for (int p = tid; p < NHH * TTT; p += 256) {
        const int h = p / TTT, t = p % TTT;
        const uint4* kr = reinterpret_cast<const uint4*>(kp + ((size_t)(b * TTT + t)) * EE + h * DHH);
        const float* qh = qs + h * DHH;
        float acc = 0.f;
        #pragma unroll
        for (int r = 0; r < 4; ++r) {
            uint4 v = kr[r];
            acc += bf2lo(v.x) * qh[8 * r + 0] + bf2hi(v.x) * qh[8 * r + 1];
            acc += bf2lo(v.y) * qh[8 * r + 2] + bf2hi(v.y) * qh[8 * r + 3];
            acc += bf2lo(v.z) * qh[8 * r + 4] + bf2hi(v.z) * qh[8 * r + 5];
            acc += bf2lo(v.w) * qh[8 * r + 6] + bf2hi(v.w) * qh[8 * r + 7];
        }
        s[h][t] = acc;
    }
    __syncthreads();

    // softmax per head: wave w handles heads 2w, 2w+1
    {
        const int wv = tid >> 6, lane = tid & 63;
        for (int hh = 0; hh < 2; ++hh) {
            const int h = wv * 2 + hh;
            float m = -1e30f;
            for (int t = lane; t < TTT; t += 64) m = fmaxf(m, s[h][t]);
            #pragma unroll
            for (int o = 32; o; o >>= 1) m = fmaxf(m, __shfl_xor(m, o));
            float sum = 0.f;
            for (int t = lane; t < TTT; t += 64) {
                float e = __expf(s[h][t] - m);
                s[h][t] = e;
                sum += e;
            }
            #pragma unroll
            for (int o = 32; o; o >>= 1) sum += __shfl_xor(sum, o);
            const float inv = 1.f / sum;
            for (int t = lane; t < TTT; t += 64) s[h][t] *= inv;
        }
    }
    __syncthreads();

    // PV: thread (h = tid>>5, d = tid&31)
    {
        const int h = tid >> 5, d = tid & 31;
        const bf16* vb = vp + (size_t)b * TTT * EE + h * DHH + d;
        float acc = 0.f;
        #pragma unroll 8
        for (int t = 0; t < TTT; ++t)
            acc += s[h][t] * __bfloat162float(vb[(size_t)t * EE]);
        actx[(size_t)b * EE + tid] = acc;
    }

    // head-averaged attention weights for batch row 0
    if (b == 0) {
        for (int t = tid; t < TTT; t += 256) {
            float a = 0.f;
            #pragma unroll
            for (int h = 0; h < NHH; ++h) a += s[h][t];
            attn_out[t * PSS + step] = a * 0.125f;
        }
    }
}

// ---------------- out_proj + heads + write next x, one block per batch row ----------------
__global__ __launch_bounds__(256)
void k_outheads(const float* __restrict__ actx, const float* __restrict__ opw, const float* __restrict__ opb,
                const float* __restrict__ h2, const float* __restrict__ mu_w, const float* __restrict__ mu_b,
                const float* __restrict__ ps_w, const float* __restrict__ ps_b,
                const float* __restrict__ zxs, float* __restrict__ inp,
                float* __restrict__ out_mu, float* __restrict__ out_sigma, int step) {
    const int b = blockIdx.x;
    const int tid = threadIdx.x;
    __shared__ float as_[EE];
    __shared__ float rm[4], rp[4];

    as_[tid] = actx[(size_t)b * EE + tid];
    __syncthreads();

    // ctx[tid] = out_proj(actx)
    const float* wr = opw + (size_t)tid * EE;
    float acc = opb[tid];
    #pragma unroll 8
    for (int i = 0; i < EE; ++i) acc += as_[i] * wr[i];
    inp[(size_t)b * INP1 + 69 + tid] = acc;   // ctx feeds next step's lstm1 input

    // heads: oc = [h2 | ctx]
    const float hv = h2[(size_t)b * EE + tid];
    float pm = hv * mu_w[tid] + acc * mu_w[EE + tid];
    float pp = hv * ps_w[tid] + acc * ps_w[EE + tid];
    #pragma unroll
    for (int o = 32; o; o >>= 1) {
        pm += __shfl_xor(pm, o);
        pp += __shfl_xor(pp, o);
    }
    const int wv = tid >> 6, lane = tid & 63;
    if (lane == 0) { rm[wv] = pm; rp[wv] = pp; }
    __syncthreads();
    if (tid == 0) {
        float m = rm[0] + rm[1] + rm[2] + rm[3] + mu_b[0];
        float p = rp[0] + rp[1] + rp[2] + rp[3] + ps_b[0];
        out_mu[b * PSS + step] = m;
        out_sigma[b * PSS + step] = (p > 20.f) ? p : log1pf(__expf(p));
    }

    // x_{t+1}
    if (tid < NCOV && step + 1 < PSS)
        inp[(size_t)b * INP1 + tid] =
            zxs[b * ((STARTT + PSS) * NCOV) + (STARTT + step + 1) * NCOV + tid];
}

// ---------------- launch ----------------
extern "C" void kernel_launch(void* const* d_in, const int* in_sizes, int n_in,
                              void* d_out, int out_size, void* d_ws, size_t ws_size,
                              hipStream_t stream) {
    const float* zxs       = (const float*)d_in[0];
    const float* key       = (const float*)d_in[1];
    const float* value     = (const float*)d_in[2];
    const float* idx_embed = (const float*)d_in[3];
    const float* w_ih1     = (const float*)d_in[4];
    const float* w_hh1     = (const float*)d_in[5];
    const float* b_ih1     = (const float*)d_in[6];
    const float* b_hh1     = (const float*)d_in[7];
    const float* w_ih2     = (const float*)d_in[8];
    const float* w_hh2     = (const float*)d_in[9];
    const float* b_ih2     = (const float*)d_in[10];
    const float* b_hh2     = (const float*)d_in[11];
    const float* in_proj_w = (const float*)d_in[12];
    const float* in_proj_b = (const float*)d_in[13];
    const float* opw       = (const float*)d_in[14];
    const float* opb       = (const float*)d_in[15];
    const float* mu_w      = (const float*)d_in[16];
    const float* mu_b      = (const float*)d_in[17];
    const float* ps_w      = (const float*)d_in[18];
    const float* ps_b      = (const float*)d_in[19];
    float* out = (float*)d_out;

    // workspace layout
    char* ws = (char*)d_ws;
    bf16* kp = (bf16*)ws;
    bf16* vp = kp + (size_t)BB * TTT * EE;
    float* f = (float*)(vp + (size_t)BB * TTT * EE);
    float* inp    = f; f += BB * INP1;
    float* h1     = f; f += BB * LHH;
    float* c1     = f; f += BB * LHH;
    float* h2     = f; f += BB * EE;
    float* c2     = f; f += BB * EE;
    float* gates1 = f; f += BB * 4 * LHH;
    float* gates2 = f; f += BB * 4 * EE;
    float* actx   = f; f += BB * EE;
    float* bsum1  = f; f += 4 * LHH;
    float* bsum2  = f; f += 4 * EE;

    const float* wq = in_proj_w;
    const float* wk = in_proj_w + EE * EE;
    const float* wv = in_proj_w + 2 * EE * EE;
    const float* bq = in_proj_b;
    const float* bk = in_proj_b + EE;
    const float* bv = in_proj_b + 2 * EE;

    // init: zero h1,c1,h2,c2 (contiguous); build inp; bias sums
    k_zero<<<2048, 256, 0, stream>>>(h1, BB * (2 * LHH + 2 * EE));
    k_init_inp<<<(BB * INP1 + 255) / 256, 256, 0, stream>>>(inp, idx_embed, zxs);
    k_bsum<<<(4 * LHH + 255) / 256, 256, 0, stream>>>(b_ih1, b_hh1, bsum1, 4 * LHH);
    k_bsum<<<(4 * EE + 255) / 256, 256, 0, stream>>>(b_ih2, b_hh2, bsum2, 4 * EE);

    // hoisted K/V projections -> bf16
    k_gemm<false, true><<<dim3(BB * TTT / 64, EE / 64), 256, 0, stream>>>(
        key, EE, wk, EE, nullptr, 0, nullptr, 0, bk, kp, EE);
    k_gemm<false, true><<<dim3(BB * TTT / 64, EE / 64), 256, 0, stream>>>(
        value, EE, wv, EE, nullptr, 0, nullptr, 0, bv, vp, EE);

    for (int t = 0; t < PSS; ++t) {
        // gates1 = inp@w_ih1.T + h1@w_hh1.T + (b_ih1+b_hh1)
        k_gemm<true, false><<<dim3(BB / 64, 4 * LHH / 64), 256, 0, stream>>>(
            inp, INP1, w_ih1, INP1, h1, LHH, w_hh1, LHH, bsum1, gates1, 4 * LHH);
        k_lstm_pw<<<BB * LHH / 256, 256, 0, stream>>>(gates1, h1, c1, LHH);
        // gates2 = h1@w_ih2.T + h2@w_hh2.T + (b_ih2+b_hh2)
        k_gemm<true, false><<<dim3(BB / 64, 4 * EE / 64), 256, 0, stream>>>(
            h1, LHH, w_ih2, LHH, h2, EE, w_hh2, EE, bsum2, gates2, 4 * EE);
        k_lstm_pw<<<BB * EE / 256, 256, 0, stream>>>(gates2, h2, c2, EE);
        // attention (q-proj fused) -> actx; writes attention weights for b=0
        k_attn<<<BB, 256, 0, stream>>>(h2, wq, bq, kp, vp, actx, out + 2 * BB * PSS, t);
        // out_proj + mu/sigma heads + stage next x
        k_outheads<<<BB, 256, 0, stream>>>(actx, opw, opb, h2, mu_w, mu_b, ps_w, ps_b,
                                           zxs, inp, out, out + BB * PSS, t);
    }
}

// Round 3
// 6545.129 us; speedup vs baseline: 2.0066x; 2.0066x over previous
//
#include <hip/hip_runtime.h>
#include <hip/hip_bf16.h>

#define BB    512
#define TTT   336
#define EE    256
#define LHH   512
#define NHH   8
#define DHH   32
#define PSS   48
#define STARTT 336
#define NCOV  5
#define XW1   352          // xh1 width: 5 x + 64 embed + 256 ctx + 27 pad
#define KP1   864          // 352 + 512
#define KP2   768          // 512 + 256
#define COFF  69           // ctx offset in xh1

typedef __hip_bfloat16 bf16;
typedef __bf16 bf16x8 __attribute__((ext_vector_type(8)));
typedef float  f32x4  __attribute__((ext_vector_type(4)));

__device__ __forceinline__ float sigf(float x) { return 1.f / (1.f + __expf(-x)); }
__device__ __forceinline__ float bf2lo(unsigned u) { return __uint_as_float(u << 16); }
__device__ __forceinline__ float bf2hi(unsigned u) { return __uint_as_float(u & 0xffff0000u); }

// ---------------- setup kernels ----------------
__global__ void k_zero(float* __restrict__ p, int n) {
    for (int i = blockIdx.x * blockDim.x + threadIdx.x; i < n; i += gridDim.x * blockDim.x)
        p[i] = 0.f;
}

// Wc1 [2048][864]: cols 0..324 = w_ih1, 325..351 = 0, 352..863 = w_hh1
__global__ void k_cvt_wc1(const float* __restrict__ wih, const float* __restrict__ whh,
                          bf16* __restrict__ Wc) {
    int i = blockIdx.x * blockDim.x + threadIdx.x;
    if (i >= 2048 * KP1) return;
    int n = i / KP1, k = i % KP1;
    float v = (k < 325) ? wih[n * 325 + k] : ((k >= 352) ? whh[n * 512 + (k - 352)] : 0.f);
    Wc[i] = __float2bfloat16(v);
}

// Wc2 [1024][768]: cols 0..511 = w_ih2, 512..767 = w_hh2
__global__ void k_cvt_wc2(const float* __restrict__ wih, const float* __restrict__ whh,
                          bf16* __restrict__ Wc) {
    int i = blockIdx.x * blockDim.x + threadIdx.x;
    if (i >= 1024 * KP2) return;
    int n = i / KP2, k = i % KP2;
    float v = (k < 512) ? wih[n * 512 + k] : whh[n * 256 + (k - 512)];
    Wc[i] = __float2bfloat16(v);
}

__global__ void k_cvt(const float* __restrict__ src, bf16* __restrict__ dst, int n) {
    int i = blockIdx.x * blockDim.x + threadIdx.x;
    if (i < n) dst[i] = __float2bfloat16(src[i]);
}

__global__ void k_bsum(const float* __restrict__ a, const float* __restrict__ b,
                       float* __restrict__ o, int n) {
    int i = blockIdx.x * blockDim.x + threadIdx.x;
    if (i < n) o[i] = a[i] + b[i];
}

// xh1 [512][352] bf16: [x(5) | embed(64) | ctx=0(256) | pad=0(27)]
__global__ void k_init_xh1(bf16* __restrict__ xh1, const float* __restrict__ idx_embed,
                           const float* __restrict__ zxs) {
    int i = blockIdx.x * blockDim.x + threadIdx.x;
    if (i >= BB * XW1) return;
    int b = i / XW1, k = i % XW1;
    float v = 0.f;
    if (k < NCOV)      v = zxs[b * ((STARTT + PSS) * NCOV) + STARTT * NCOV + k];
    else if (k < COFF) v = idx_embed[b * 64 + (k - NCOV)];
    xh1[i] = __float2bfloat16(v);
}

// ---------------- fused LSTM step: gates GEMM (MFMA) + pointwise ----------------
// C_gates[512][4H] = concat_k(A0[512][32*K0T], A1[512][32*K1T]) @ Wc[4H][KP]^T + bsum
// then h,c update. Block: 64 rows x 64 h-units (=256 gate cols). 4 waves.
// LDS swizzle: logical 16B chunk c of row r stored at chunk (c + (r>>1)) & 3.
template<int H, int K0T, int K1T>
__global__ __launch_bounds__(256)
void k_lstm_step(const bf16* __restrict__ A0, int ld0,
                 const bf16* __restrict__ A1, int ld1,
                 const bf16* __restrict__ Wc, const float* __restrict__ bsum,
                 float* __restrict__ c, bf16* __restrict__ hdst,
                 float* __restrict__ outF) {
    constexpr int KP = (K0T + K1T) * 32;
    __shared__ __align__(16) bf16 As[64 * 32];
    __shared__ __align__(16) bf16 Bs[256 * 32];
    const int tid = threadIdx.x;
    const int w = tid >> 6, l = tid & 63;
    const int row0 = blockIdx.x * 64, col0 = blockIdx.y * 64;
    const int srow = tid >> 2, schunk = tid & 3;
    const int fr = l & 15, fc = l >> 4;
    f32x4 acc[16] = {};

    for (int kt = 0; kt < K0T + K1T; ++kt) {
        // stage A tile (64 x 32)
        {
            const bf16* base = (kt < K0T) ? A0 : A1;
            const int ldx    = (kt < K0T) ? ld0 : ld1;
            const int kk     = (kt < K0T) ? kt : (kt - K0T);
            uint4 va = *(const uint4*)(base + (size_t)(row0 + srow) * ldx + kk * 32 + schunk * 8);
            *(uint4*)(As + srow * 32 + (((schunk + (srow >> 1)) & 3) << 3)) = va;
        }
        // stage B tile (256 gate-cols x 32)
        #pragma unroll
        for (int i = 0; i < 4; ++i) {
            int n = i * 64 + srow;                       // 0..255: gate = n>>6, unit = n&63
            int gr = (n >> 6) * H + col0 + (n & 63);     // row in Wc
            uint4 vb = *(const uint4*)(Wc + (size_t)gr * KP + kt * 32 + schunk * 8);
            *(uint4*)(Bs + n * 32 + (((schunk + (n >> 1)) & 3) << 3)) = vb;
        }
        __syncthreads();
        const int ar = w * 16 + fr;
        bf16x8 a = *(const bf16x8*)(As + ar * 32 + (((fc + (ar >> 1)) & 3) << 3));
        #pragma unroll
        for (int nt = 0; nt < 16; ++nt) {
            const int br = nt * 16 + fr;
            bf16x8 b = *(const bf16x8*)(Bs + br * 32 + (((fc + (br >> 1)) & 3) << 3));
            acc[nt] = __builtin_amdgcn_mfma_f32_16x16x32_bf16(a, b, acc[nt], 0, 0, 0);
        }
        __syncthreads();
    }

    // epilogue: acc[gate*4+u][r] -> row = row0+w*16+fc*4+r, h-unit = col0+u*16+fr
    #pragma unroll
    for (int u = 0; u < 4; ++u) {
        const int hu = col0 + u * 16 + fr;
        const float bi = bsum[hu], bff = bsum[H + hu], bg = bsum[2 * H + hu], bo = bsum[3 * H + hu];
        #pragma unroll
        for (int r = 0; r < 4; ++r) {
            const int R = row0 + w * 16 + fc * 4 + r;
            float gi = acc[u][r]      + bi;
            float gf = acc[4 + u][r]  + bff;
            float gg = acc[8 + u][r]  + bg;
            float go = acc[12 + u][r] + bo;
            float cn = sigf(gf) * c[(size_t)R * H + hu] + sigf(gi) * tanhf(gg);
            c[(size_t)R * H + hu] = cn;
            float h = sigf(go) * tanhf(cn);
            hdst[(size_t)R * H + hu] = __float2bfloat16(h);
            if (outF) outF[(size_t)R * H + hu] = h;
        }
    }
}

// ---------------- K/V projection (one-time): out[M][256] = bf16(X@Wb^T + bias) ----------------
__global__ __launch_bounds__(256)
void k_kvproj(const float* __restrict__ X, const bf16* __restrict__ Wb,
              const float* __restrict__ bias, bf16* __restrict__ out) {
    __shared__ __align__(16) bf16 As[64 * 32];
    __shared__ __align__(16) bf16 Bs[256 * 32];
    const int tid = threadIdx.x;
    const int w = tid >> 6, l = tid & 63;
    const int row0 = blockIdx.x * 64;
    const int srow = tid >> 2, schunk = tid & 3;
    const int fr = l & 15, fc = l >> 4;
    f32x4 acc[16] = {};

    for (int kt = 0; kt < 8; ++kt) {
        {
            const float* ap = X + (size_t)(row0 + srow) * EE + kt * 32 + schunk * 8;
            float4 v0 = *(const float4*)ap, v1 = *(const float4*)(ap + 4);
            union { bf16 h[8]; uint4 u; } pk;
            pk.h[0] = __float2bfloat16(v0.x); pk.h[1] = __float2bfloat16(v0.y);
            pk.h[2] = __float2bfloat16(v0.z); pk.h[3] = __float2bfloat16(v0.w);
            pk.h[4] = __float2bfloat16(v1.x); pk.h[5] = __float2bfloat16(v1.y);
            pk.h[6] = __float2bfloat16(v1.z); pk.h[7] = __float2bfloat16(v1.w);
            *(uint4*)(As + srow * 32 + (((schunk + (srow >> 1)) & 3) << 3)) = pk.u;
        }
        #pragma unroll
        for (int i = 0; i < 4; ++i) {
            int n = i * 64 + srow;
            uint4 vb = *(const uint4*)(Wb + (size_t)n * EE + kt * 32 + schunk * 8);
            *(uint4*)(Bs + n * 32 + (((schunk + (n >> 1)) & 3) << 3)) = vb;
        }
        __syncthreads();
        const int ar = w * 16 + fr;
        bf16x8 a = *(const bf16x8*)(As + ar * 32 + (((fc + (ar >> 1)) & 3) << 3));
        #pragma unroll
        for (int nt = 0; nt < 16; ++nt) {
            const int br = nt * 16 + fr;
            bf16x8 b = *(const bf16x8*)(Bs + br * 32 + (((fc + (br >> 1)) & 3) << 3));
            acc[nt] = __builtin_amdgcn_mfma_f32_16x16x32_bf16(a, b, acc[nt], 0, 0, 0);
        }
        __syncthreads();
    }
    #pragma unroll
    for (int nt = 0; nt < 16; ++nt) {
        const int col = nt * 16 + fr;
        const float bv = bias[col];
        #pragma unroll
        for (int r = 0; r < 4; ++r) {
            const int R = row0 + w * 16 + fc * 4 + r;
            out[(size_t)R * EE + col] = __float2bfloat16(acc[nt][r] + bv);
        }
    }
}

// ---------------- attention + out_proj + heads + next-x staging ----------------
__global__ __launch_bounds__(256)
void k_attn_out(const float* __restrict__ h2f, const float* __restrict__ wq, const float* __restrict__ bq,
                const bf16* __restrict__ kp, const bf16* __restrict__ vp,
                const float* __restrict__ opw, const float* __restrict__ opb,
                const float* __restrict__ mu_w, const float* __restrict__ mu_b,
                const float* __restrict__ ps_w, const float* __restrict__ ps_b,
                const float* __restrict__ zxs, bf16* __restrict__ xh1,
                float* __restrict__ out_mu, float* __restrict__ out_sigma,
                float* __restrict__ attn_out, int step) {
    const int b = blockIdx.x;
    const int tid = threadIdx.x;
    __shared__ float h2s[EE];
    __shared__ float qs[EE];
    __shared__ float s[NHH][TTT];
    __shared__ float rm[4], rp[4];

    h2s[tid] = h2f[(size_t)b * EE + tid];
    __syncthreads();

    // q projection (scale folded)
    {
        const float* wr = wq + (size_t)tid * EE;
        float acc = bq[tid];
        #pragma unroll 8
        for (int i = 0; i < EE; ++i) acc += h2s[i] * wr[i];
        qs[tid] = acc * 0.17677669529663689f;
    }
    __syncthreads();

    // scores
    for (int p = tid; p < NHH * TTT; p += 256) {
        const int h = p / TTT, t = p % TTT;
        const uint4* kr = reinterpret_cast<const uint4*>(kp + ((size_t)(b * TTT + t)) * EE + h * DHH);
        const float* qh = qs + h * DHH;
        float acc = 0.f;
        #pragma unroll
        for (int r = 0; r < 4; ++r) {
            uint4 v = kr[r];
            acc += bf2lo(v.x) * qh[8 * r + 0] + bf2hi(v.x) * qh[8 * r + 1];
            acc += bf2lo(v.y) * qh[8 * r + 2] + bf2hi(v.y) * qh[8 * r + 3];
            acc += bf2lo(v.z) * qh[8 * r + 4] + bf2hi(v.z) * qh[8 * r + 5];
            acc += bf2lo(v.w) * qh[8 * r + 6] + bf2hi(v.w) * qh[8 * r + 7];
        }
        s[h][t] = acc;
    }
    __syncthreads();

    // softmax per head
    {
        const int wv = tid >> 6, lane = tid & 63;
        for (int hh = 0; hh < 2; ++hh) {
            const int h = wv * 2 + hh;
            float m = -1e30f;
            for (int t = lane; t < TTT; t += 64) m = fmaxf(m, s[h][t]);
            #pragma unroll
            for (int o = 32; o; o >>= 1) m = fmaxf(m, __shfl_xor(m, o));
            float sum = 0.f;
            for (int t = lane; t < TTT; t += 64) {
                float e = __expf(s[h][t] - m);
                s[h][t] = e;
                sum += e;
            }
            #pragma unroll
            for (int o = 32; o; o >>= 1) sum += __shfl_xor(sum, o);
            const float inv = 1.f / sum;
            for (int t = lane; t < TTT; t += 64) s[h][t] *= inv;
        }
    }
    __syncthreads();

    // head-averaged attention weights for b==0
    if (b == 0) {
        for (int t = tid; t < TTT; t += 256) {
            float a = 0.f;
            #pragma unroll
            for (int h = 0; h < NHH; ++h) a += s[h][t];
            attn_out[t * PSS + step] = a * 0.125f;
        }
    }

    // PV
    float av;
    {
        const int h = tid >> 5, d = tid & 31;
        const bf16* vb = vp + (size_t)b * TTT * EE + h * DHH + d;
        float acc = 0.f;
        #pragma unroll 8
        for (int t = 0; t < TTT; ++t)
            acc += s[h][t] * __bfloat162float(vb[(size_t)t * EE]);
        av = acc;
    }
    qs[tid] = av;   // reuse qs as attention-output vector
    __syncthreads();

    // out_proj -> ctx
    {
        const float* wr = opw + (size_t)tid * EE;
        float ctxv = opb[tid];
        #pragma unroll 8
        for (int i = 0; i < EE; ++i) ctxv += qs[i] * wr[i];
        xh1[(size_t)b * XW1 + COFF + tid] = __float2bfloat16(ctxv);

        // heads: oc = [h2 | ctx]
        const float hv = h2s[tid];
        float pm = hv * mu_w[tid] + ctxv * mu_w[EE + tid];
        float pp = hv * ps_w[tid] + ctxv * ps_w[EE + tid];
        #pragma unroll
        for (int o = 32; o; o >>= 1) {
            pm += __shfl_xor(pm, o);
            pp += __shfl_xor(pp, o);
        }
        const int wv = tid >> 6, lane = tid & 63;
        if (lane == 0) { rm[wv] = pm; rp[wv] = pp; }
    }
    __syncthreads();
    if (tid == 0) {
        float m = rm[0] + rm[1] + rm[2] + rm[3] + mu_b[0];
        float p = rp[0] + rp[1] + rp[2] + rp[3] + ps_b[0];
        out_mu[b * PSS + step] = m;
        out_sigma[b * PSS + step] = (p > 20.f) ? p : log1pf(__expf(p));
    }

    // stage x_{t+1}
    if (tid < NCOV && step + 1 < PSS)
        xh1[(size_t)b * XW1 + tid] =
            __float2bfloat16(zxs[b * ((STARTT + PSS) * NCOV) + (STARTT + step + 1) * NCOV + tid]);
}

// ---------------- launch ----------------
extern "C" void kernel_launch(void* const* d_in, const int* in_sizes, int n_in,
                              void* d_out, int out_size, void* d_ws, size_t ws_size,
                              hipStream_t stream) {
    const float* zxs       = (const float*)d_in[0];
    const float* key       = (const float*)d_in[1];
    const float* value     = (const float*)d_in[2];
    const float* idx_embed = (const float*)d_in[3];
    const float* w_ih1     = (const float*)d_in[4];
    const float* w_hh1     = (const float*)d_in[5];
    const float* b_ih1     = (const float*)d_in[6];
    const float* b_hh1     = (const float*)d_in[7];
    const float* w_ih2     = (const float*)d_in[8];
    const float* w_hh2     = (const float*)d_in[9];
    const float* b_ih2     = (const float*)d_in[10];
    const float* b_hh2     = (const float*)d_in[11];
    const float* in_proj_w = (const float*)d_in[12];
    const float* in_proj_b = (const float*)d_in[13];
    const float* opw       = (const float*)d_in[14];
    const float* opb       = (const float*)d_in[15];
    const float* mu_w      = (const float*)d_in[16];
    const float* mu_b      = (const float*)d_in[17];
    const float* ps_w      = (const float*)d_in[18];
    const float* ps_b      = (const float*)d_in[19];
    float* out = (float*)d_out;

    // workspace carve (16B-aligned pieces)
    char* ws = (char*)d_ws;
    bf16* kp    = (bf16*)ws;                       ws += (size_t)BB * TTT * EE * 2;
    bf16* vp    = (bf16*)ws;                       ws += (size_t)BB * TTT * EE * 2;
    bf16* wkvb  = (bf16*)ws;                       ws += (size_t)2 * EE * EE * 2;
    bf16* Wc1   = (bf16*)ws;                       ws += (size_t)2048 * KP1 * 2;
    bf16* Wc2   = (bf16*)ws;                       ws += (size_t)1024 * KP2 * 2;
    bf16* xh1   = (bf16*)ws;                       ws += (size_t)BB * XW1 * 2;
    bf16* h1b0  = (bf16*)ws;                       ws += (size_t)BB * LHH * 2;
    bf16* h1b1  = (bf16*)ws;                       ws += (size_t)BB * LHH * 2;
    bf16* h2b0  = (bf16*)ws;                       ws += (size_t)BB * EE * 2;
    bf16* h2b1  = (bf16*)ws;                       ws += (size_t)BB * EE * 2;
    float* c1   = (float*)ws;                      ws += (size_t)BB * LHH * 4;
    float* c2   = (float*)ws;                      ws += (size_t)BB * EE * 4;
    float* h2f  = (float*)ws;                      ws += (size_t)BB * EE * 4;
    float* bsum1 = (float*)ws;                     ws += 4 * LHH * 4;
    float* bsum2 = (float*)ws;                     ws += 4 * EE * 4;
    bf16* h1buf[2] = { h1b0, h1b1 };
    bf16* h2buf[2] = { h2b0, h2b1 };

    const float* bq = in_proj_b;
    const float* bk = in_proj_b + EE;
    const float* bv = in_proj_b + 2 * EE;
    const float* wq = in_proj_w;

    // setup
    k_cvt_wc1<<<(2048 * KP1 + 255) / 256, 256, 0, stream>>>(w_ih1, w_hh1, Wc1);
    k_cvt_wc2<<<(1024 * KP2 + 255) / 256, 256, 0, stream>>>(w_ih2, w_hh2, Wc2);
    k_cvt<<<(2 * EE * EE + 255) / 256, 256, 0, stream>>>(in_proj_w + EE * EE, wkvb, 2 * EE * EE);
    k_bsum<<<(4 * LHH + 255) / 256, 256, 0, stream>>>(b_ih1, b_hh1, bsum1, 4 * LHH);
    k_bsum<<<(4 * EE + 255) / 256, 256, 0, stream>>>(b_ih2, b_hh2, bsum2, 4 * EE);
    k_init_xh1<<<(BB * XW1 + 255) / 256, 256, 0, stream>>>(xh1, idx_embed, zxs);
    // zero h1buf[0..1], h2buf[0..1] (bf16, contiguous) + c1 + c2 (fp32, contiguous after)
    k_zero<<<1024, 256, 0, stream>>>((float*)h1b0, (2 * BB * LHH + 2 * BB * EE) / 2);
    k_zero<<<1024, 256, 0, stream>>>(c1, BB * LHH + BB * EE);

    // one-time K/V projections (MFMA)
    k_kvproj<<<BB * TTT / 64, 256, 0, stream>>>(key, wkvb, bk, kp);
    k_kvproj<<<BB * TTT / 64, 256, 0, stream>>>(value, wkvb + EE * EE, bv, vp);

    for (int t = 0; t < PSS; ++t) {
        const int p = t & 1, q = (t + 1) & 1;
        // lstm1: A = [xh1 (352) | h1_{t-1} (512)]
        k_lstm_step<LHH, XW1 / 32, LHH / 32><<<dim3(BB / 64, LHH / 64), 256, 0, stream>>>(
            xh1, XW1, h1buf[p], LHH, Wc1, bsum1, c1, h1buf[q], nullptr);
        // lstm2: A = [h1_t (512) | h2_{t-1} (256)]
        k_lstm_step<EE, LHH / 32, EE / 32><<<dim3(BB / 64, EE / 64), 256, 0, stream>>>(
            h1buf[q], LHH, h2buf[p], EE, Wc2, bsum2, c2, h2buf[q], h2f);
        // attention + out_proj + heads + stage x_{t+1}
        k_attn_out<<<BB, 256, 0, stream>>>(h2f, wq, bq, kp, vp, opw, opb,
                                           mu_w, mu_b, ps_w, ps_b, zxs, xh1,
                                           out, out + BB * PSS, out + 2 * BB * PSS, t);
    }
}

// Round 4
// 5793.103 us; speedup vs baseline: 2.2671x; 1.1298x over previous
//
#include <hip/hip_runtime.h>
#include <hip/hip_bf16.h>

#define BB    512
#define TTT   336
#define EE    256
#define LHH   512
#define NHH   8
#define DHH   32
#define PSS   48
#define STARTT 336
#define NCOV  5
#define XW1   352          // xh1 width: 5 x + 64 embed + 256 ctx + 27 pad
#define KP1   864          // 352 + 512
#define KP2   768          // 512 + 256
#define COFF  69           // ctx offset in xh1
#define SPAD  340          // padded score row: 340 mod 32 = 20 -> 8 head-rows hit distinct banks

typedef __hip_bfloat16 bf16;
typedef __bf16 bf16x8 __attribute__((ext_vector_type(8)));
typedef float  f32x4  __attribute__((ext_vector_type(4)));

__device__ __forceinline__ float sigf(float x) { return 1.f / (1.f + __expf(-x)); }
__device__ __forceinline__ float bf2lo(unsigned u) { return __uint_as_float(u << 16); }
__device__ __forceinline__ float bf2hi(unsigned u) { return __uint_as_float(u & 0xffff0000u); }

// ---------------- setup kernels ----------------
__global__ void k_zero(float* __restrict__ p, int n) {
    for (int i = blockIdx.x * blockDim.x + threadIdx.x; i < n; i += gridDim.x * blockDim.x)
        p[i] = 0.f;
}

// Wc1 [2048][864]: cols 0..324 = w_ih1, 325..351 = 0, 352..863 = w_hh1
__global__ void k_cvt_wc1(const float* __restrict__ wih, const float* __restrict__ whh,
                          bf16* __restrict__ Wc) {
    int i = blockIdx.x * blockDim.x + threadIdx.x;
    if (i >= 2048 * KP1) return;
    int n = i / KP1, k = i % KP1;
    float v = (k < 325) ? wih[n * 325 + k] : ((k >= 352) ? whh[n * 512 + (k - 352)] : 0.f);
    Wc[i] = __float2bfloat16(v);
}

// Wc2 [1024][768]: cols 0..511 = w_ih2, 512..767 = w_hh2
__global__ void k_cvt_wc2(const float* __restrict__ wih, const float* __restrict__ whh,
                          bf16* __restrict__ Wc) {
    int i = blockIdx.x * blockDim.x + threadIdx.x;
    if (i >= 1024 * KP2) return;
    int n = i / KP2, k = i % KP2;
    float v = (k < 512) ? wih[n * 512 + k] : whh[n * 256 + (k - 512)];
    Wc[i] = __float2bfloat16(v);
}

__global__ void k_cvt(const float* __restrict__ src, bf16* __restrict__ dst, int n) {
    int i = blockIdx.x * blockDim.x + threadIdx.x;
    if (i < n) dst[i] = __float2bfloat16(src[i]);
}

__global__ void k_bsum(const float* __restrict__ a, const float* __restrict__ b,
                       float* __restrict__ o, int n) {
    int i = blockIdx.x * blockDim.x + threadIdx.x;
    if (i < n) o[i] = a[i] + b[i];
}

// xh1 [512][352] bf16: [x(5) | embed(64) | ctx=0(256) | pad=0(27)]
__global__ void k_init_xh1(bf16* __restrict__ xh1, const float* __restrict__ idx_embed,
                           const float* __restrict__ zxs) {
    int i = blockIdx.x * blockDim.x + threadIdx.x;
    if (i >= BB * XW1) return;
    int b = i / XW1, k = i % XW1;
    float v = 0.f;
    if (k < NCOV)      v = zxs[b * ((STARTT + PSS) * NCOV) + STARTT * NCOV + k];
    else if (k < COFF) v = idx_embed[b * 64 + (k - NCOV)];
    xh1[i] = __float2bfloat16(v);
}

// ---------------- fused LSTM step: gates GEMM (MFMA) + pointwise ----------------
template<int H, int K0T, int K1T>
__global__ __launch_bounds__(256)
void k_lstm_step(const bf16* __restrict__ A0, int ld0,
                 const bf16* __restrict__ A1, int ld1,
                 const bf16* __restrict__ Wc, const float* __restrict__ bsum,
                 float* __restrict__ c, bf16* __restrict__ hdst,
                 float* __restrict__ outF) {
    constexpr int KP = (K0T + K1T) * 32;
    __shared__ __align__(16) bf16 As[64 * 32];
    __shared__ __align__(16) bf16 Bs[256 * 32];
    const int tid = threadIdx.x;
    const int w = tid >> 6, l = tid & 63;
    const int row0 = blockIdx.x * 64, col0 = blockIdx.y * 64;
    const int srow = tid >> 2, schunk = tid & 3;
    const int fr = l & 15, fc = l >> 4;
    f32x4 acc[16] = {};

    for (int kt = 0; kt < K0T + K1T; ++kt) {
        {
            const bf16* base = (kt < K0T) ? A0 : A1;
            const int ldx    = (kt < K0T) ? ld0 : ld1;
            const int kk     = (kt < K0T) ? kt : (kt - K0T);
            uint4 va = *(const uint4*)(base + (size_t)(row0 + srow) * ldx + kk * 32 + schunk * 8);
            *(uint4*)(As + srow * 32 + (((schunk + (srow >> 1)) & 3) << 3)) = va;
        }
        #pragma unroll
        for (int i = 0; i < 4; ++i) {
            int n = i * 64 + srow;
            int gr = (n >> 6) * H + col0 + (n & 63);
            uint4 vb = *(const uint4*)(Wc + (size_t)gr * KP + kt * 32 + schunk * 8);
            *(uint4*)(Bs + n * 32 + (((schunk + (n >> 1)) & 3) << 3)) = vb;
        }
        __syncthreads();
        const int ar = w * 16 + fr;
        bf16x8 a = *(const bf16x8*)(As + ar * 32 + (((fc + (ar >> 1)) & 3) << 3));
        #pragma unroll
        for (int nt = 0; nt < 16; ++nt) {
            const int br = nt * 16 + fr;
            bf16x8 b = *(const bf16x8*)(Bs + br * 32 + (((fc + (br >> 1)) & 3) << 3));
            acc[nt] = __builtin_amdgcn_mfma_f32_16x16x32_bf16(a, b, acc[nt], 0, 0, 0);
        }
        __syncthreads();
    }

    #pragma unroll
    for (int u = 0; u < 4; ++u) {
        const int hu = col0 + u * 16 + fr;
        const float bi = bsum[hu], bff = bsum[H + hu], bg = bsum[2 * H + hu], bo = bsum[3 * H + hu];
        #pragma unroll
        for (int r = 0; r < 4; ++r) {
            const int R = row0 + w * 16 + fc * 4 + r;
            float gi = acc[u][r]      + bi;
            float gf = acc[4 + u][r]  + bff;
            float gg = acc[8 + u][r]  + bg;
            float go = acc[12 + u][r] + bo;
            float cn = sigf(gf) * c[(size_t)R * H + hu] + sigf(gi) * tanhf(gg);
            c[(size_t)R * H + hu] = cn;
            float h = sigf(go) * tanhf(cn);
            hdst[(size_t)R * H + hu] = __float2bfloat16(h);
            if (outF) outF[(size_t)R * H + hu] = h;
        }
    }
}

// ---------------- K/V projection (one-time): out[M][256] = bf16(X@Wb^T + bias) ----------------
__global__ __launch_bounds__(256)
void k_kvproj(const float* __restrict__ X, const bf16* __restrict__ Wb,
              const float* __restrict__ bias, bf16* __restrict__ out) {
    __shared__ __align__(16) bf16 As[64 * 32];
    __shared__ __align__(16) bf16 Bs[256 * 32];
    const int tid = threadIdx.x;
    const int w = tid >> 6, l = tid & 63;
    const int row0 = blockIdx.x * 64;
    const int srow = tid >> 2, schunk = tid & 3;
    const int fr = l & 15, fc = l >> 4;
    f32x4 acc[16] = {};

    for (int kt = 0; kt < 8; ++kt) {
        {
            const float* ap = X + (size_t)(row0 + srow) * EE + kt * 32 + schunk * 8;
            float4 v0 = *(const float4*)ap, v1 = *(const float4*)(ap + 4);
            union { bf16 h[8]; uint4 u; } pk;
            pk.h[0] = __float2bfloat16(v0.x); pk.h[1] = __float2bfloat16(v0.y);
            pk.h[2] = __float2bfloat16(v0.z); pk.h[3] = __float2bfloat16(v0.w);
            pk.h[4] = __float2bfloat16(v1.x); pk.h[5] = __float2bfloat16(v1.y);
            pk.h[6] = __float2bfloat16(v1.z); pk.h[7] = __float2bfloat16(v1.w);
            *(uint4*)(As + srow * 32 + (((schunk + (srow >> 1)) & 3) << 3)) = pk.u;
        }
        #pragma unroll
        for (int i = 0; i < 4; ++i) {
            int n = i * 64 + srow;
            uint4 vb = *(const uint4*)(Wb + (size_t)n * EE + kt * 32 + schunk * 8);
            *(uint4*)(Bs + n * 32 + (((schunk + (n >> 1)) & 3) << 3)) = vb;
        }
        __syncthreads();
        const int ar = w * 16 + fr;
        bf16x8 a = *(const bf16x8*)(As + ar * 32 + (((fc + (ar >> 1)) & 3) << 3));
        #pragma unroll
        for (int nt = 0; nt < 16; ++nt) {
            const int br = nt * 16 + fr;
            bf16x8 b = *(const bf16x8*)(Bs + br * 32 + (((fc + (br >> 1)) & 3) << 3));
            acc[nt] = __builtin_amdgcn_mfma_f32_16x16x32_bf16(a, b, acc[nt], 0, 0, 0);
        }
        __syncthreads();
    }
    #pragma unroll
    for (int nt = 0; nt < 16; ++nt) {
        const int col = nt * 16 + fr;
        const float bv = bias[col];
        #pragma unroll
        for (int r = 0; r < 4; ++r) {
            const int R = row0 + w * 16 + fc * 4 + r;
            out[(size_t)R * EE + col] = __float2bfloat16(acc[nt][r] + bv);
        }
    }
}

// ---------------- attention + out_proj + heads + next-x staging ----------------
// Thread map for K/V streaming: tt = tid>>5 (8 consecutive T-rows), ck = tid&31
// (32 uint4 chunks of a 512B row). head = ck>>2. Fully coalesced 1KB/wave loads.
__global__ __launch_bounds__(256)
void k_attn_out(const float* __restrict__ h2f, const bf16* __restrict__ wqb, const float* __restrict__ bq,
                const bf16* __restrict__ kp, const bf16* __restrict__ vp,
                const bf16* __restrict__ opwb, const float* __restrict__ opb,
                const float* __restrict__ mu_w, const float* __restrict__ mu_b,
                const float* __restrict__ ps_w, const float* __restrict__ ps_b,
                const float* __restrict__ zxs, bf16* __restrict__ xh1,
                float* __restrict__ out_mu, float* __restrict__ out_sigma,
                float* __restrict__ attn_out, int step) {
    const int b = blockIdx.x;
    const int tid = threadIdx.x;
    __shared__ float h2s[EE];
    __shared__ float qs[EE];
    __shared__ float s[NHH][SPAD];
    __shared__ float rm[4], rp[4];

    h2s[tid] = h2f[(size_t)b * EE + tid];
    __syncthreads();

    // q projection (bf16 weights, scale folded)
    {
        const uint4* wr = (const uint4*)(wqb + (size_t)tid * EE);
        float acc = bq[tid];
        #pragma unroll
        for (int i = 0; i < EE / 8; ++i) {
            uint4 v = wr[i];
            const float* hh = h2s + i * 8;
            acc += bf2lo(v.x) * hh[0] + bf2hi(v.x) * hh[1] + bf2lo(v.y) * hh[2] + bf2hi(v.y) * hh[3]
                 + bf2lo(v.z) * hh[4] + bf2hi(v.z) * hh[5] + bf2lo(v.w) * hh[6] + bf2hi(v.w) * hh[7];
        }
        qs[tid] = acc * 0.17677669529663689f;
    }
    __syncthreads();

    const int tt = tid >> 5, ck = tid & 31;
    const int head = ck >> 2;

    // scores: coalesced K stream; q chunk (8 vals) held in registers
    {
        float q0 = qs[ck * 8 + 0], q1 = qs[ck * 8 + 1], q2 = qs[ck * 8 + 2], q3 = qs[ck * 8 + 3];
        float q4 = qs[ck * 8 + 4], q5 = qs[ck * 8 + 5], q6 = qs[ck * 8 + 6], q7 = qs[ck * 8 + 7];
        const bf16* kb = kp + (size_t)b * TTT * EE;
        #pragma unroll 3
        for (int t0 = 0; t0 < TTT; t0 += 8) {
            const int t = t0 + tt;
            uint4 v = *(const uint4*)(kb + (size_t)t * EE + ck * 8);
            float p = bf2lo(v.x) * q0 + bf2hi(v.x) * q1 + bf2lo(v.y) * q2 + bf2hi(v.y) * q3
                    + bf2lo(v.z) * q4 + bf2hi(v.z) * q5 + bf2lo(v.w) * q6 + bf2hi(v.w) * q7;
            p += __shfl_xor(p, 1);
            p += __shfl_xor(p, 2);
            if ((ck & 3) == 0) s[head][t] = p;
        }
    }
    __syncthreads();

    // softmax per head: wave w handles heads 2w, 2w+1
    {
        const int wv = tid >> 6, lane = tid & 63;
        for (int hh = 0; hh < 2; ++hh) {
            const int h = wv * 2 + hh;
            float m = -1e30f;
            for (int t = lane; t < TTT; t += 64) m = fmaxf(m, s[h][t]);
            #pragma unroll
            for (int o = 32; o; o >>= 1) m = fmaxf(m, __shfl_xor(m, o));
            float sum = 0.f;
            for (int t = lane; t < TTT; t += 64) {
                float e = __expf(s[h][t] - m);
                s[h][t] = e;
                sum += e;
            }
            #pragma unroll
            for (int o = 32; o; o >>= 1) sum += __shfl_xor(sum, o);
            const float inv = 1.f / sum;
            for (int t = lane; t < TTT; t += 64) s[h][t] *= inv;
        }
    }
    __syncthreads();

    // head-averaged attention weights for b==0 (must precede red-overlay of s)
    if (b == 0) {
        for (int t = tid; t < TTT; t += 256) {
            float a = 0.f;
            #pragma unroll
            for (int h = 0; h < NHH; ++h) a += s[h][t];
            attn_out[t * PSS + step] = a * 0.125f;
        }
    }

    // PV: coalesced V stream, 8 d-elements per thread, 8 t-phases
    float a0 = 0.f, a1 = 0.f, a2 = 0.f, a3 = 0.f, a4 = 0.f, a5 = 0.f, a6 = 0.f, a7 = 0.f;
    {
        const bf16* vb = vp + (size_t)b * TTT * EE;
        #pragma unroll 3
        for (int t0 = 0; t0 < TTT; t0 += 8) {
            const int t = t0 + tt;
            uint4 v = *(const uint4*)(vb + (size_t)t * EE + ck * 8);
            const float a = s[head][t];
            a0 += a * bf2lo(v.x); a1 += a * bf2hi(v.x);
            a2 += a * bf2lo(v.y); a3 += a * bf2hi(v.y);
            a4 += a * bf2lo(v.z); a5 += a * bf2hi(v.z);
            a6 += a * bf2lo(v.w); a7 += a * bf2hi(v.w);
        }
    }
    __syncthreads();                 // all s reads done; overlay reduction scratch on s
    {
        float* red = &s[0][0];       // red[j][tt][ck], 8*8*32 = 2048 floats
        red[0 * 256 + tt * 32 + ck] = a0;
        red[1 * 256 + tt * 32 + ck] = a1;
        red[2 * 256 + tt * 32 + ck] = a2;
        red[3 * 256 + tt * 32 + ck] = a3;
        red[4 * 256 + tt * 32 + ck] = a4;
        red[5 * 256 + tt * 32 + ck] = a5;
        red[6 * 256 + tt * 32 + ck] = a6;
        red[7 * 256 + tt * 32 + ck] = a7;
        __syncthreads();
        // thread (tt,ck) -> output element ck*8 + tt
        float av = 0.f;
        #pragma unroll
        for (int k = 0; k < 8; ++k) av += red[tt * 256 + k * 32 + ck];
        __syncthreads();
        qs[ck * 8 + tt] = av;        // attention output vector
    }
    __syncthreads();

    // out_proj -> ctx (bf16 weights) + heads
    {
        const uint4* wr = (const uint4*)(opwb + (size_t)tid * EE);
        float ctxv = opb[tid];
        #pragma unroll
        for (int i = 0; i < EE / 8; ++i) {
            uint4 v = wr[i];
            const float* hh = qs + i * 8;
            ctxv += bf2lo(v.x) * hh[0] + bf2hi(v.x) * hh[1] + bf2lo(v.y) * hh[2] + bf2hi(v.y) * hh[3]
                  + bf2lo(v.z) * hh[4] + bf2hi(v.z) * hh[5] + bf2lo(v.w) * hh[6] + bf2hi(v.w) * hh[7];
        }
        xh1[(size_t)b * XW1 + COFF + tid] = __float2bfloat16(ctxv);

        const float hv = h2s[tid];
        float pm = hv * mu_w[tid] + ctxv * mu_w[EE + tid];
        float pp = hv * ps_w[tid] + ctxv * ps_w[EE + tid];
        #pragma unroll
        for (int o = 32; o; o >>= 1) {
            pm += __shfl_xor(pm, o);
            pp += __shfl_xor(pp, o);
        }
        const int wv = tid >> 6, lane = tid & 63;
        if (lane == 0) { rm[wv] = pm; rp[wv] = pp; }
    }
    __syncthreads();
    if (tid == 0) {
        float m = rm[0] + rm[1] + rm[2] + rm[3] + mu_b[0];
        float p = rp[0] + rp[1] + rp[2] + rp[3] + ps_b[0];
        out_mu[b * PSS + step] = m;
        out_sigma[b * PSS + step] = (p > 20.f) ? p : log1pf(__expf(p));
    }

    // stage x_{t+1}
    if (tid < NCOV && step + 1 < PSS)
        xh1[(size_t)b * XW1 + tid] =
            __float2bfloat16(zxs[b * ((STARTT + PSS) * NCOV) + (STARTT + step + 1) * NCOV + tid]);
}

// ---------------- launch ----------------
extern "C" void kernel_launch(void* const* d_in, const int* in_sizes, int n_in,
                              void* d_out, int out_size, void* d_ws, size_t ws_size,
                              hipStream_t stream) {
    const float* zxs       = (const float*)d_in[0];
    const float* key       = (const float*)d_in[1];
    const float* value     = (const float*)d_in[2];
    const float* idx_embed = (const float*)d_in[3];
    const float* w_ih1     = (const float*)d_in[4];
    const float* w_hh1     = (const float*)d_in[5];
    const float* b_ih1     = (const float*)d_in[6];
    const float* b_hh1     = (const float*)d_in[7];
    const float* w_ih2     = (const float*)d_in[8];
    const float* w_hh2     = (const float*)d_in[9];
    const float* b_ih2     = (const float*)d_in[10];
    const float* b_hh2     = (const float*)d_in[11];
    const float* in_proj_w = (const float*)d_in[12];
    const float* in_proj_b = (const float*)d_in[13];
    const float* opw       = (const float*)d_in[14];
    const float* opb       = (const float*)d_in[15];
    const float* mu_w      = (const float*)d_in[16];
    const float* mu_b      = (const float*)d_in[17];
    const float* ps_w      = (const float*)d_in[18];
    const float* ps_b      = (const float*)d_in[19];
    float* out = (float*)d_out;

    // workspace carve (16B-aligned pieces)
    char* ws = (char*)d_ws;
    bf16* kp    = (bf16*)ws;                       ws += (size_t)BB * TTT * EE * 2;
    bf16* vp    = (bf16*)ws;                       ws += (size_t)BB * TTT * EE * 2;
    bf16* wkvb  = (bf16*)ws;                       ws += (size_t)2 * EE * EE * 2;
    bf16* wqb   = (bf16*)ws;                       ws += (size_t)EE * EE * 2;
    bf16* opwb  = (bf16*)ws;                       ws += (size_t)EE * EE * 2;
    bf16* Wc1   = (bf16*)ws;                       ws += (size_t)2048 * KP1 * 2;
    bf16* Wc2   = (bf16*)ws;                       ws += (size_t)1024 * KP2 * 2;
    bf16* xh1   = (bf16*)ws;                       ws += (size_t)BB * XW1 * 2;
    bf16* h1b0  = (bf16*)ws;                       ws += (size_t)BB * LHH * 2;
    bf16* h1b1  = (bf16*)ws;                       ws += (size_t)BB * LHH * 2;
    bf16* h2b0  = (bf16*)ws;                       ws += (size_t)BB * EE * 2;
    bf16* h2b1  = (bf16*)ws;                       ws += (size_t)BB * EE * 2;
    float* c1   = (float*)ws;                      ws += (size_t)BB * LHH * 4;
    float* c2   = (float*)ws;                      ws += (size_t)BB * EE * 4;
    float* h2f  = (float*)ws;                      ws += (size_t)BB * EE * 4;
    float* bsum1 = (float*)ws;                     ws += 4 * LHH * 4;
    float* bsum2 = (float*)ws;                     ws += 4 * EE * 4;
    bf16* h1buf[2] = { h1b0, h1b1 };
    bf16* h2buf[2] = { h2b0, h2b1 };

    const float* bq = in_proj_b;
    const float* bk = in_proj_b + EE;
    const float* bv = in_proj_b + 2 * EE;

    // setup
    k_cvt_wc1<<<(2048 * KP1 + 255) / 256, 256, 0, stream>>>(w_ih1, w_hh1, Wc1);
    k_cvt_wc2<<<(1024 * KP2 + 255) / 256, 256, 0, stream>>>(w_ih2, w_hh2, Wc2);
    k_cvt<<<(2 * EE * EE + 255) / 256, 256, 0, stream>>>(in_proj_w + EE * EE, wkvb, 2 * EE * EE);
    k_cvt<<<(EE * EE + 255) / 256, 256, 0, stream>>>(in_proj_w, wqb, EE * EE);
    k_cvt<<<(EE * EE + 255) / 256, 256, 0, stream>>>(opw, opwb, EE * EE);
    k_bsum<<<(4 * LHH + 255) / 256, 256, 0, stream>>>(b_ih1, b_hh1, bsum1, 4 * LHH);
    k_bsum<<<(4 * EE + 255) / 256, 256, 0, stream>>>(b_ih2, b_hh2, bsum2, 4 * EE);
    k_init_xh1<<<(BB * XW1 + 255) / 256, 256, 0, stream>>>(xh1, idx_embed, zxs);
    k_zero<<<1024, 256, 0, stream>>>((float*)h1b0, (2 * BB * LHH + 2 * BB * EE) / 2);
    k_zero<<<1024, 256, 0, stream>>>(c1, BB * LHH + BB * EE);

    // one-time K/V projections (MFMA)
    k_kvproj<<<BB * TTT / 64, 256, 0, stream>>>(key, wkvb, bk, kp);
    k_kvproj<<<BB * TTT / 64, 256, 0, stream>>>(value, wkvb + EE * EE, bv, vp);

    for (int t = 0; t < PSS; ++t) {
        const int p = t & 1, q = (t + 1) & 1;
        // lstm1: A = [xh1 (352) | h1_{t-1} (512)]
        k_lstm_step<LHH, XW1 / 32, LHH / 32><<<dim3(BB / 64, LHH / 64), 256, 0, stream>>>(
            xh1, XW1, h1buf[p], LHH, Wc1, bsum1, c1, h1buf[q], nullptr);
        // lstm2: A = [h1_t (512) | h2_{t-1} (256)]
        k_lstm_step<EE, LHH / 32, EE / 32><<<dim3(BB / 64, EE / 64), 256, 0, stream>>>(
            h1buf[q], LHH, h2buf[p], EE, Wc2, bsum2, c2, h2buf[q], h2f);
        // attention + out_proj + heads + stage x_{t+1}
        k_attn_out<<<BB, 256, 0, stream>>>(h2f, wqb, bq, kp, vp, opwb, opb,
                                           mu_w, mu_b, ps_w, ps_b, zxs, xh1,
                                           out, out + BB * PSS, out + 2 * BB * PSS, t);
    }
}